// Round 1
// baseline (446.014 us; speedup 1.0000x reference)
//
#include <hip/hip_runtime.h>
#include <hip/hip_bf16.h>

// Net_40089224741482 round 16:
//  - dgemm_core: 3-stage LDS pipeline with counted s_waitcnt vmcnt(N) (never
//    drains to 0 in the main loop) + raw s_barrier — removes the __syncthreads
//    vmcnt(0) prefetch drain (guide T3+T4; m218/m248 evidence at K=1024).
//  - expert GEMM: fused distance epilogue. Each 32-col fragment == one expert;
//    tanh + (c-a)^2 + 5-step shfl_xor reduce within the 32-lane half, write
//    dist[B][N] f32 (4MB) instead of z (64MB f16).
//  - final_fused replaced by slim final_softmax (wave per row, dist+values only).

typedef _Float16 half8 __attribute__((ext_vector_type(8)));
typedef _Float16 half4v __attribute__((ext_vector_type(4)));
typedef float floatx16 __attribute__((ext_vector_type(16)));

namespace {
constexpr int kB = 4096, kS = 128, kA = 32, kH = 1024, kN = 256;
constexpr size_t al(size_t x) { return (x + 255) & ~size_t(255); }
constexpr size_t OFF_FLAG  = 0;
constexpr size_t OFF_S16   = 256;
constexpr size_t OFF_WEXPT = OFF_S16   + al((size_t)kB * kS * 2);
constexpr size_t OFF_WV1T  = OFF_WEXPT + al((size_t)kN * kA * kH * 2);
constexpr size_t OFF_WL1T  = OFF_WV1T  + (size_t)kS * kH * 2;   // contiguous with WV1T
constexpr size_t OFF_WV2T  = OFF_WL1T  + al((size_t)kS * kH * 2);
constexpr size_t OFF_WV3T  = OFF_WV2T  + al((size_t)kH * kH * 2);
constexpr size_t OFF_WV4T  = OFF_WV3T  + al((size_t)kH * kH * 2);
constexpr size_t OFF_BUFC  = OFF_WV4T  + al((size_t)kH * kN * 2);
constexpr size_t OFF_B2V   = OFF_BUFC  + al((size_t)kB * 2 * kH * 2);
constexpr size_t OFF_B3    = OFF_B2V   + al((size_t)kB * kH * 2);
constexpr size_t OFF_VAL   = OFF_B3    + al((size_t)kB * kH * 2);
constexpr size_t OFF_DIST  = OFF_VAL   + al((size_t)kB * kN * 4);
} // namespace

__device__ __forceinline__ float ldraw(const void* p, size_t i, int bf) {
    if (bf) return __uint_as_float(((unsigned)((const unsigned short*)p)[i]) << 16);
    return ((const float*)p)[i];
}

__device__ __forceinline__ float4 ldraw4(const void* p, size_t i, int bf) {
    if (bf) {
        ushort4 u = *(const ushort4*)((const unsigned short*)p + i);
        return make_float4(__uint_as_float((unsigned)u.x << 16),
                           __uint_as_float((unsigned)u.y << 16),
                           __uint_as_float((unsigned)u.z << 16),
                           __uint_as_float((unsigned)u.w << 16));
    }
    return *(const float4*)((const float*)p + i);
}

__device__ __forceinline__ void gl_lds16(const _Float16* g, _Float16* l) {
    __builtin_amdgcn_global_load_lds(
        (const __attribute__((address_space(1))) unsigned int*)g,
        (__attribute__((address_space(3))) unsigned int*)l, 16, 0, 0);
}

template <int N>
__device__ __forceinline__ void waitcnt_vm() {
    if constexpr (N == 0)      asm volatile("s_waitcnt vmcnt(0)" ::: "memory");
    else if constexpr (N == 2) asm volatile("s_waitcnt vmcnt(2)" ::: "memory");
    else if constexpr (N == 4) asm volatile("s_waitcnt vmcnt(4)" ::: "memory");
    else if constexpr (N == 6) asm volatile("s_waitcnt vmcnt(6)" ::: "memory");
    else if constexpr (N == 8) asm volatile("s_waitcnt vmcnt(8)" ::: "memory");
    else static_assert(N == 0, "unsupported vmcnt");
}
__device__ __forceinline__ void lgkm0() { asm volatile("s_waitcnt lgkmcnt(0)" ::: "memory"); }

__device__ __forceinline__ float fast_tanh(float x) {
    x = fminf(9.f, fmaxf(-9.f, x));
    float e = __expf(2.f * x);
    return (e - 1.f) * __builtin_amdgcn_rcpf(e + 1.f);
}

// --- dtype detection, parallel (fp32 low-16 = uniform mantissa; bf16-packed -> exp near 127)
__global__ void detect_kernel(const unsigned int* __restrict__ s_raw, int* __restrict__ flag) {
    __shared__ int cnt;
    if (threadIdx.x == 0) cnt = 0;
    __syncthreads();
    const unsigned e = (s_raw[threadIdx.x] >> 7) & 0xFFu;
    int c = (e >= 118u && e <= 135u) ? 1 : 0;
    for (int off = 32; off > 0; off >>= 1) c += __shfl_down(c, off);
    if ((threadIdx.x & 63) == 0) atomicAdd(&cnt, c);
    __syncthreads();
    if (threadIdx.x == 0) *flag = (cnt > 128) ? 1 : 0;
}

// --- ALL weight transposes + the s->f16 convert in ONE dispatch.
struct TDesc { const void* src; _Float16* dst; int K; int N; int tiles; };
struct TPack { TDesc d[7]; };

__global__ void transpose_all(TPack p, const int* __restrict__ flag) {
    __shared__ float tile[32][33];
    const int bf = *flag;
    int bid = blockIdx.x;
    int i = 0;
    while (bid >= p.d[i].tiles) { bid -= p.d[i].tiles; ++i; }
    const void* src = p.d[i].src;
    _Float16* dst = p.d[i].dst;
    const int tx = threadIdx.x, ty = threadIdx.y;  // tx 0..7, ty 0..31
    const int K = p.d[i].K, N = p.d[i].N;
    if (K == 0) {  // straight convert
        const int lin = ty * 8 + tx;
        const size_t base = (size_t)bid * 4096;
#pragma unroll
        for (int t = 0; t < 4; ++t) {
            const size_t idx = base + (size_t)t * 1024 + (size_t)lin * 4;
            float4 v = ldraw4(src, idx, bf);
            half4v o = {(_Float16)v.x, (_Float16)v.y, (_Float16)v.z, (_Float16)v.w};
            *(half4v*)(dst + idx) = o;
        }
        return;
    }
    const int tpz = (N >> 5) * (K >> 5);
    const int z = bid / tpz, r = bid - z * tpz;
    const int n0 = (r % (N >> 5)) * 32, k0 = (r / (N >> 5)) * 32;
    const size_t zo = (size_t)z * K * N;
    float4 v = ldraw4(src, zo + (size_t)(k0 + ty) * N + n0 + tx * 4, bf);
    tile[ty][tx * 4 + 0] = v.x;
    tile[ty][tx * 4 + 1] = v.y;
    tile[ty][tx * 4 + 2] = v.z;
    tile[ty][tx * 4 + 3] = v.w;
    __syncthreads();
    half4v o;
#pragma unroll
    for (int j = 0; j < 4; ++j) o[j] = (_Float16)tile[tx * 4 + j][ty];
    *(half4v*)(dst + zo + (size_t)(n0 + ty) * K + k0 + tx * 4) = o;
}

// --- GEMM argument pack
struct GArgs {
    const _Float16* A;
    const _Float16* Bt;
    const void* bias;
    const void* bias2;   // split-bias epilogue (fused gemm1+gemm5)
    void* C;
    const void* a_raw;   // fuse path: raw actions [B][kA]
    float* dist;         // fuse path: [B][kN] output
    int split;           // col < split -> bias[col], else bias2[col-split]
    int N, K, lda, Mt, Nt, relu, of16, fuse;
};

// --- core: 3-stage MFMA GEMM, counted-vmcnt pipeline, fragment-order LDS,
// global_load_lds w16, XCD swizzle. C[M,N] = act(A[M,K](lda) @ Bt[N,K]^T + bias).
template <int TM, int TN, int WM, int WN>
__device__ __forceinline__ void dgemm_core(const GArgs& g, int bid, const int* flagp) {
    constexpr int NT = WM * WN * 64;
    constexpr int BK = 32;
    constexpr int NST = 3;                 // pipeline depth (prefetch distance 2)
    constexpr int MI = TM / WM / 32, NI = TN / WN / 32;
    constexpr int ACH = TM * BK / 8;
    constexpr int BCH = TN * BK / 8;
    constexpr int AT = (ACH + NT - 1) / NT;
    constexpr int BT = (BCH + NT - 1) / NT;
    constexpr int LPS = AT + BT;           // gl_lds instrs per wave per stage
    __shared__ _Float16 As[NST * ACH * 8];
    __shared__ _Float16 Bs[NST * BCH * 8];

    const int tid = threadIdx.x;
    const int lane = tid & 63;
    const int w = tid >> 6, wr = w / WN, wc = w % WN;
    const int N = g.N, K = g.K, lda = g.lda;

    int mt, nt;
    if ((g.Mt & 7) == 0 && (g.Nt & 7) == 0) {
        const int xcd = bid & 7, loc = bid >> 3;
        const int Bn = g.Nt >> 3;
        const int sr = loc / (8 * Bn);
        const int rem = loc - sr * (8 * Bn);
        mt = sr * 8 + (rem & 7);
        nt = xcd * Bn + (rem >> 3);
    } else {
        mt = bid % g.Mt;
        nt = bid / g.Mt;
    }
    const int m0 = mt * TM, n0 = nt * TN;

    const _Float16* gAsrc[AT];
    _Float16* lAdst[AT];
#pragma unroll
    for (int t = 0; t < AT; ++t) {
        int c = t * NT + tid;
        if (c >= ACH) c = ACH - 1;
        const int ks = c / (TM * 2), rem = c % (TM * 2);
        const int row = (rem >> 6) * 32 + (rem & 31);
        const int kcol = ks * 16 + ((rem >> 5) & 1) * 8;
        gAsrc[t] = g.A + (size_t)(m0 + row) * lda + kcol;
        lAdst[t] = As + c * 8;
    }
    const _Float16* gBsrc[BT];
    _Float16* lBdst[BT];
#pragma unroll
    for (int t = 0; t < BT; ++t) {
        int c = t * NT + tid;
        if (c >= BCH) c = BCH - 1;
        const int ks = c / (TN * 2), rem = c % (TN * 2);
        const int row = (rem >> 6) * 32 + (rem & 31);
        const int kcol = ks * 16 + ((rem >> 5) & 1) * 8;
        gBsrc[t] = g.Bt + (size_t)(n0 + row) * K + kcol;
        lBdst[t] = Bs + c * 8;
    }

    auto issue = [&](int k0, int st) {
#pragma unroll
        for (int t = 0; t < AT; ++t)
            if ((t + 1) * NT <= ACH || t * NT + tid < ACH)
                gl_lds16(gAsrc[t] + k0, lAdst[t] + st * ACH * 8);
#pragma unroll
        for (int t = 0; t < BT; ++t)
            if ((t + 1) * NT <= BCH || t * NT + tid < BCH)
                gl_lds16(gBsrc[t] + k0, lBdst[t] + st * BCH * 8);
    };

    floatx16 acc[MI][NI];
#pragma unroll
    for (int mi = 0; mi < MI; ++mi)
#pragma unroll
        for (int ni = 0; ni < NI; ++ni)
#pragma unroll
            for (int i = 0; i < 16; ++i) acc[mi][ni][i] = 0.f;

    auto compute = [&](int st) {
        const int ao = st * ACH * 8, bo = st * BCH * 8;
#pragma unroll
        for (int ks = 0; ks < 2; ++ks) {
            half8 af[MI], bf[NI];
#pragma unroll
            for (int mi = 0; mi < MI; ++mi)
                af[mi] = *(const half8*)(As + ao + ((size_t)(ks * TM * 2 + (wr * MI + mi) * 64 + lane)) * 8);
#pragma unroll
            for (int ni = 0; ni < NI; ++ni)
                bf[ni] = *(const half8*)(Bs + bo + ((size_t)(ks * TN * 2 + (wc * NI + ni) * 64 + lane)) * 8);
#pragma unroll
            for (int mi = 0; mi < MI; ++mi)
#pragma unroll
                for (int ni = 0; ni < NI; ++ni)
                    acc[mi][ni] = __builtin_amdgcn_mfma_f32_32x32x16_f16(af[mi], bf[ni], acc[mi][ni], 0, 0, 0);
        }
    };

    // --- 3-stage counted-vmcnt pipeline ---
    issue(0, 0);
    if (BK < K) issue(BK, 1);
    if (2 * BK < K) issue(2 * BK, 2);
    int st = 0;
    for (int k0 = 0; k0 < K; k0 += BK) {
        // wait until this stage's loads have landed (own oldest); newer stages stay in flight
        if (k0 + 2 * BK < K)      waitcnt_vm<2 * LPS>();
        else if (k0 + BK < K)     waitcnt_vm<LPS>();
        else                      waitcnt_vm<0>();
        __builtin_amdgcn_s_barrier();        // all waves' stage-k0 loads landed
        asm volatile("" ::: "memory");
        __builtin_amdgcn_sched_barrier(0);
        compute(st);
        lgkm0();                              // own LDS reads of this buffer done
        __builtin_amdgcn_s_barrier();        // all waves done reading buffer st
        if (k0 + 3 * BK < K) issue(k0 + 3 * BK, st);
        st = (st == NST - 1) ? 0 : st + 1;
    }

    const int bf_ = *flagp;
    const int am = lane & 31;
    const int half = lane >> 5;

    if (g.fuse) {
        // fused tanh + ||c-a||: each 32-col fragment is one expert; sum d^2 over
        // the 32 a-lanes via 5-step shfl_xor (stays within the 32-lane half).
#pragma unroll
        for (int mi = 0; mi < MI; ++mi)
#pragma unroll
            for (int ni = 0; ni < NI; ++ni) {
                const int Rb = m0 + (wr * MI + mi) * 32;
                const int Cb = n0 + (wc * NI + ni) * 32 + am;
                const int e = Cb >> 5;  // expert index, uniform per fragment
                const float bv = ldraw(g.bias, Cb, bf_);
#pragma unroll
                for (int rr = 0; rr < 16; ++rr) {
                    const int row = Rb + (rr & 3) + 8 * (rr >> 2) + 4 * half;
                    const float c = fast_tanh(acc[mi][ni][rr] + bv);
                    const float av = ldraw(g.a_raw, (size_t)row * kA + am, bf_);
                    const float d = c - av;
                    float d2 = d * d;
                    d2 += __shfl_xor(d2, 1);
                    d2 += __shfl_xor(d2, 2);
                    d2 += __shfl_xor(d2, 4);
                    d2 += __shfl_xor(d2, 8);
                    d2 += __shfl_xor(d2, 16);
                    if (am == 0) g.dist[(size_t)row * kN + e] = sqrtf(d2 + 0.01f);
                }
            }
        return;
    }

#pragma unroll
    for (int mi = 0; mi < MI; ++mi)
#pragma unroll
        for (int ni = 0; ni < NI; ++ni) {
            const int Rb = m0 + (wr * MI + mi) * 32;
            const int Cb = n0 + (wc * NI + ni) * 32 + am;
            const float bv = (Cb < g.split) ? ldraw(g.bias, Cb, bf_)
                                            : ldraw(g.bias2, Cb - g.split, bf_);
#pragma unroll
            for (int rr = 0; rr < 16; ++rr) {
                const int row = Rb + (rr & 3) + 8 * (rr >> 2) + 4 * half;
                float x = acc[mi][ni][rr] + bv;
                if (g.relu) x = fmaxf(x, 0.f);
                if (g.of16) ((_Float16*)g.C)[(size_t)row * N + Cb] = (_Float16)x;
                else ((float*)g.C)[(size_t)row * N + Cb] = x;
            }
        }
}

template <int TM, int TN, int WM, int WN>
__launch_bounds__(WM * WN * 64, 2)
__global__ void dgemm_one(GArgs g, const int* __restrict__ flagp) {
    dgemm_core<TM, TN, WM, WN>(g, blockIdx.x, flagp);
}

// --- slim final: softmax(-dist) . values, one wave per batch row
__launch_bounds__(256)
__global__ void final_softmax(const float* __restrict__ dist, const float* __restrict__ values,
                              const int* __restrict__ flag, void* __restrict__ out) {
    const int row = blockIdx.x * 4 + (threadIdx.x >> 6);
    const int lane = threadIdx.x & 63;
    const float4 d4 = *(const float4*)(dist + (size_t)row * kN + lane * 4);
    const float4 v4 = *(const float4*)(values + (size_t)row * kN + lane * 4);
    float m = fminf(fminf(d4.x, d4.y), fminf(d4.z, d4.w));
#pragma unroll
    for (int off = 32; off > 0; off >>= 1) m = fminf(m, __shfl_xor(m, off));
    const float w0 = expf(m - d4.x), w1 = expf(m - d4.y);
    const float w2 = expf(m - d4.z), w3 = expf(m - d4.w);
    float ws = (w0 + w1) + (w2 + w3);
    float wv = fmaf(w0, v4.x, fmaf(w1, v4.y, fmaf(w2, v4.z, w3 * v4.w)));
#pragma unroll
    for (int off = 32; off > 0; off >>= 1) {
        ws += __shfl_xor(ws, off);
        wv += __shfl_xor(wv, off);
    }
    if (lane == 0) {
        const float o = wv / ws;
        if (*flag) ((__hip_bfloat16*)out)[row] = __float2bfloat16(o);
        else       ((float*)out)[row] = o;
    }
}

extern "C" void kernel_launch(void* const* d_in, const int* in_sizes, int n_in,
                              void* d_out, int out_size, void* d_ws, size_t ws_size,
                              hipStream_t stream) {
    (void)in_sizes; (void)n_in; (void)out_size; (void)ws_size;
    char* ws = (char*)d_ws;
    int* flag = (int*)(ws + OFF_FLAG);
    _Float16* s16   = (_Float16*)(ws + OFF_S16);
    _Float16* wexpt = (_Float16*)(ws + OFF_WEXPT);
    _Float16* wv1t  = (_Float16*)(ws + OFF_WV1T);  // wl1t contiguous after -> [2048x128]
    _Float16* wl1t  = (_Float16*)(ws + OFF_WL1T);
    _Float16* wv2t  = (_Float16*)(ws + OFF_WV2T);
    _Float16* wv3t  = (_Float16*)(ws + OFF_WV3T);
    _Float16* wv4t  = (_Float16*)(ws + OFF_WV4T);
    _Float16* bufC  = (_Float16*)(ws + OFF_BUFC);  // [4096 x 2048]: h1 | hloc
    _Float16* b2v   = (_Float16*)(ws + OFF_B2V);
    _Float16* b3    = (_Float16*)(ws + OFF_B3);
    float* values   = (float*)(ws + OFF_VAL);
    float* distb    = (float*)(ws + OFF_DIST);

    detect_kernel<<<1, 256, 0, stream>>>((const unsigned int*)d_in[0], flag);

    TPack tp;
    tp.d[0] = {d_in[2],  wv1t,  kS, kH, (kH / 32) * (kS / 32)};          // 128
    tp.d[1] = {d_in[10], wl1t,  kS, kH, (kH / 32) * (kS / 32)};          // 128
    tp.d[2] = {d_in[4],  wv2t,  kH, kH, (kH / 32) * (kH / 32)};          // 1024
    tp.d[3] = {d_in[6],  wv3t,  kH, kH, (kH / 32) * (kH / 32)};          // 1024
    tp.d[4] = {d_in[8],  wv4t,  kH, kN, (kN / 32) * (kH / 32)};          // 256
    tp.d[5] = {d_in[12], wexpt, kH, kA, kN * (kA / 32) * (kH / 32)};     // 8192
    tp.d[6] = {d_in[0],  s16,   0,  kB * kS, (kB * kS) / 4096};          // 128 (convert)
    int total_tiles = 0;
    for (int i = 0; i < 7; ++i) total_tiles += tp.d[i].tiles;            // 10880
    transpose_all<<<total_tiles, dim3(8, 32), 0, stream>>>(tp, flag);

    const int BIG = 1 << 30;
    // fused gemm1+gemm5: bufC[4096x2048] = relu(s16 @ [wv1t;wl1t]^T + [bv1;bl1])
    {
        GArgs g{s16, wv1t, d_in[3], d_in[11], bufC, nullptr, nullptr, kH,
                2 * kH, kS, kS, kB / 64, (2 * kH) / 64, 1, 1, 0};
        dgemm_one<64, 64, 2, 2><<<(kB / 64) * ((2 * kH) / 64), 256, 0, stream>>>(g, flag);
    }
    // gemm2: b2v = relu(bufC[:, :1024] @ wv2t^T + bv2)
    {
        GArgs g{bufC, wv2t, d_in[5], d_in[5], b2v, nullptr, nullptr, BIG,
                kH, kH, 2 * kH, kB / 128, kH / 128, 1, 1, 0};
        dgemm_one<128, 128, 2, 2><<<(kB / 128) * (kH / 128), 256, 0, stream>>>(g, flag);
    }
    // gemm3: b3 = relu(b2v @ wv3t^T + bv3)
    {
        GArgs g{b2v, wv3t, d_in[7], d_in[7], b3, nullptr, nullptr, BIG,
                kH, kH, kH, kB / 128, kH / 128, 1, 1, 0};
        dgemm_one<128, 128, 2, 2><<<(kB / 128) * (kH / 128), 256, 0, stream>>>(g, flag);
    }
    // gemm4: values = b3 @ wv4t^T + bv4 (f32 out)
    {
        GArgs g{b3, wv4t, d_in[9], d_in[9], values, nullptr, nullptr, BIG,
                kN, kH, kH, kB / 64, kN / 64, 0, 0, 0};
        dgemm_one<64, 64, 2, 2><<<(kB / 64) * (kN / 64), 256, 0, stream>>>(g, flag);
    }
    // expert heads + fused distance: dist[B][N] = ||tanh(h@Wexp+bexp) - a||
    {
        GArgs g{bufC + kH, wexpt, d_in[13], d_in[13], nullptr, d_in[1], distb,
                BIG, kN * kA, kH, 2 * kH, kB / 256, (kN * kA) / 256, 0, 0, 1};
        dgemm_one<256, 256, 4, 4><<<(kB / 256) * ((kN * kA) / 256), 1024, 0, stream>>>(g, flag);
    }
    // softmax over experts + value readout
    final_softmax<<<kB / 4, 256, 0, stream>>>(distb, values, flag, d_out);
}

// Round 2
// 377.704 us; speedup vs baseline: 1.1809x; 1.1809x over previous
//
#include <hip/hip_runtime.h>
#include <hip/hip_bf16.h>

// Net_40089224741482 round 17:
//  - Diagnosis from r16 counters: main loop is LDS-read-BW-bound (1KB ds_read per
//    MFMA at MI=NI=2), and the fused epilogue's scattered 4B stores caused ~150MB
//    of RMW write amplification (WRITE 76->225MB, FETCH 49->160MB).
//  - expert GEMM: WM=2,WN=4 (8 waves, 512thr) -> MI=4,NI=2 = 0.75KB LDS/MFMA.
//  - fused dist epilogue: a-tile staged in LDS (reuse As), dist staged in LDS
//    (reuse Bs), single coalesced copy-out. No partial-line RMW.
//  - pipeline: NST=4, depth-3 prefetch, ONE s_barrier per BK step (vm-wait before
//    barrier), counted vmcnt never drains mid-loop, setprio(1) around MFMA.

typedef _Float16 half8 __attribute__((ext_vector_type(8)));
typedef _Float16 half4v __attribute__((ext_vector_type(4)));
typedef float floatx16 __attribute__((ext_vector_type(16)));

namespace {
constexpr int kB = 4096, kS = 128, kA = 32, kH = 1024, kN = 256;
constexpr size_t al(size_t x) { return (x + 255) & ~size_t(255); }
constexpr size_t OFF_FLAG  = 0;
constexpr size_t OFF_S16   = 256;
constexpr size_t OFF_WEXPT = OFF_S16   + al((size_t)kB * kS * 2);
constexpr size_t OFF_WV1T  = OFF_WEXPT + al((size_t)kN * kA * kH * 2);
constexpr size_t OFF_WL1T  = OFF_WV1T  + (size_t)kS * kH * 2;   // contiguous with WV1T
constexpr size_t OFF_WV2T  = OFF_WL1T  + al((size_t)kS * kH * 2);
constexpr size_t OFF_WV3T  = OFF_WV2T  + al((size_t)kH * kH * 2);
constexpr size_t OFF_WV4T  = OFF_WV3T  + al((size_t)kH * kH * 2);
constexpr size_t OFF_BUFC  = OFF_WV4T  + al((size_t)kH * kN * 2);
constexpr size_t OFF_B2V   = OFF_BUFC  + al((size_t)kB * 2 * kH * 2);
constexpr size_t OFF_B3    = OFF_B2V   + al((size_t)kB * kH * 2);
constexpr size_t OFF_VAL   = OFF_B3    + al((size_t)kB * kH * 2);
constexpr size_t OFF_DIST  = OFF_VAL   + al((size_t)kB * kN * 4);
} // namespace

__device__ __forceinline__ float ldraw(const void* p, size_t i, int bf) {
    if (bf) return __uint_as_float(((unsigned)((const unsigned short*)p)[i]) << 16);
    return ((const float*)p)[i];
}

__device__ __forceinline__ float4 ldraw4(const void* p, size_t i, int bf) {
    if (bf) {
        ushort4 u = *(const ushort4*)((const unsigned short*)p + i);
        return make_float4(__uint_as_float((unsigned)u.x << 16),
                           __uint_as_float((unsigned)u.y << 16),
                           __uint_as_float((unsigned)u.z << 16),
                           __uint_as_float((unsigned)u.w << 16));
    }
    return *(const float4*)((const float*)p + i);
}

__device__ __forceinline__ void gl_lds16(const _Float16* g, _Float16* l) {
    __builtin_amdgcn_global_load_lds(
        (const __attribute__((address_space(1))) unsigned int*)g,
        (__attribute__((address_space(3))) unsigned int*)l, 16, 0, 0);
}

template <int N>
__device__ __forceinline__ void waitcnt_vm() {
    if constexpr (N == 0)      asm volatile("s_waitcnt vmcnt(0)" ::: "memory");
    else if constexpr (N == 2) asm volatile("s_waitcnt vmcnt(2)" ::: "memory");
    else if constexpr (N == 4) asm volatile("s_waitcnt vmcnt(4)" ::: "memory");
    else if constexpr (N == 6) asm volatile("s_waitcnt vmcnt(6)" ::: "memory");
    else if constexpr (N == 8) asm volatile("s_waitcnt vmcnt(8)" ::: "memory");
    else if constexpr (N == 16) asm volatile("s_waitcnt vmcnt(16)" ::: "memory");
    else static_assert(N == 0, "unsupported vmcnt");
}
__device__ __forceinline__ void lgkm0() { asm volatile("s_waitcnt lgkmcnt(0)" ::: "memory"); }

__device__ __forceinline__ float fast_tanh(float x) {
    x = fminf(9.f, fmaxf(-9.f, x));
    float e = __expf(2.f * x);
    return (e - 1.f) * __builtin_amdgcn_rcpf(e + 1.f);
}

// --- dtype detection, parallel (fp32 low-16 = uniform mantissa; bf16-packed -> exp near 127)
__global__ void detect_kernel(const unsigned int* __restrict__ s_raw, int* __restrict__ flag) {
    __shared__ int cnt;
    if (threadIdx.x == 0) cnt = 0;
    __syncthreads();
    const unsigned e = (s_raw[threadIdx.x] >> 7) & 0xFFu;
    int c = (e >= 118u && e <= 135u) ? 1 : 0;
    for (int off = 32; off > 0; off >>= 1) c += __shfl_down(c, off);
    if ((threadIdx.x & 63) == 0) atomicAdd(&cnt, c);
    __syncthreads();
    if (threadIdx.x == 0) *flag = (cnt > 128) ? 1 : 0;
}

// --- ALL weight transposes + the s->f16 convert in ONE dispatch.
struct TDesc { const void* src; _Float16* dst; int K; int N; int tiles; };
struct TPack { TDesc d[7]; };

__global__ void transpose_all(TPack p, const int* __restrict__ flag) {
    __shared__ float tile[32][33];
    const int bf = *flag;
    int bid = blockIdx.x;
    int i = 0;
    while (bid >= p.d[i].tiles) { bid -= p.d[i].tiles; ++i; }
    const void* src = p.d[i].src;
    _Float16* dst = p.d[i].dst;
    const int tx = threadIdx.x, ty = threadIdx.y;  // tx 0..7, ty 0..31
    const int K = p.d[i].K, N = p.d[i].N;
    if (K == 0) {  // straight convert
        const int lin = ty * 8 + tx;
        const size_t base = (size_t)bid * 4096;
#pragma unroll
        for (int t = 0; t < 4; ++t) {
            const size_t idx = base + (size_t)t * 1024 + (size_t)lin * 4;
            float4 v = ldraw4(src, idx, bf);
            half4v o = {(_Float16)v.x, (_Float16)v.y, (_Float16)v.z, (_Float16)v.w};
            *(half4v*)(dst + idx) = o;
        }
        return;
    }
    const int tpz = (N >> 5) * (K >> 5);
    const int z = bid / tpz, r = bid - z * tpz;
    const int n0 = (r % (N >> 5)) * 32, k0 = (r / (N >> 5)) * 32;
    const size_t zo = (size_t)z * K * N;
    float4 v = ldraw4(src, zo + (size_t)(k0 + ty) * N + n0 + tx * 4, bf);
    tile[ty][tx * 4 + 0] = v.x;
    tile[ty][tx * 4 + 1] = v.y;
    tile[ty][tx * 4 + 2] = v.z;
    tile[ty][tx * 4 + 3] = v.w;
    __syncthreads();
    half4v o;
#pragma unroll
    for (int j = 0; j < 4; ++j) o[j] = (_Float16)tile[tx * 4 + j][ty];
    *(half4v*)(dst + zo + (size_t)(n0 + ty) * K + k0 + tx * 4) = o;
}

// --- GEMM argument pack
struct GArgs {
    const _Float16* A;
    const _Float16* Bt;
    const void* bias;
    const void* bias2;   // split-bias epilogue (fused gemm1+gemm5)
    void* C;
    const void* a_raw;   // fuse path: raw actions [B][kA]
    float* dist;         // fuse path: [B][kN] output
    int split;           // col < split -> bias[col], else bias2[col-split]
    int N, K, lda, Mt, Nt, relu, of16, fuse;
};

// --- core: 4-stage MFMA GEMM, depth-3 counted-vmcnt pipeline, ONE barrier per
// BK step, fragment-order LDS, global_load_lds w16, XCD swizzle.
template <int TM, int TN, int WM, int WN>
__device__ __forceinline__ void dgemm_core(const GArgs& g, int bid, const int* flagp) {
    constexpr int NT = WM * WN * 64;
    constexpr int BK = 32;
    constexpr int NST = 4;                 // LDS stages (prefetch distance 3)
    constexpr int MI = TM / WM / 32, NI = TN / WN / 32;
    constexpr int ACH = TM * BK / 8;
    constexpr int BCH = TN * BK / 8;
    constexpr int AT = (ACH + NT - 1) / NT;
    constexpr int BT = (BCH + NT - 1) / NT;
    constexpr int LPS = AT + BT;           // gl_lds instrs per wave per stage
    __shared__ _Float16 As[NST * ACH * 8];
    __shared__ _Float16 Bs[NST * BCH * 8];

    const int tid = threadIdx.x;
    const int lane = tid & 63;
    const int w = tid >> 6, wr = w / WN, wc = w % WN;
    const int N = g.N, K = g.K, lda = g.lda;

    int mt, nt;
    if ((g.Mt & 7) == 0 && (g.Nt & 7) == 0) {
        const int xcd = bid & 7, loc = bid >> 3;
        const int Bn = g.Nt >> 3;
        const int sr = loc / (8 * Bn);
        const int rem = loc - sr * (8 * Bn);
        mt = sr * 8 + (rem & 7);
        nt = xcd * Bn + (rem >> 3);
    } else {
        mt = bid % g.Mt;
        nt = bid / g.Mt;
    }
    const int m0 = mt * TM, n0 = nt * TN;

    const _Float16* gAsrc[AT];
    _Float16* lAdst[AT];
#pragma unroll
    for (int t = 0; t < AT; ++t) {
        int c = t * NT + tid;
        if (c >= ACH) c = ACH - 1;
        const int ks = c / (TM * 2), rem = c % (TM * 2);
        const int row = (rem >> 6) * 32 + (rem & 31);
        const int kcol = ks * 16 + ((rem >> 5) & 1) * 8;
        gAsrc[t] = g.A + (size_t)(m0 + row) * lda + kcol;
        lAdst[t] = As + c * 8;
    }
    const _Float16* gBsrc[BT];
    _Float16* lBdst[BT];
#pragma unroll
    for (int t = 0; t < BT; ++t) {
        int c = t * NT + tid;
        if (c >= BCH) c = BCH - 1;
        const int ks = c / (TN * 2), rem = c % (TN * 2);
        const int row = (rem >> 6) * 32 + (rem & 31);
        const int kcol = ks * 16 + ((rem >> 5) & 1) * 8;
        gBsrc[t] = g.Bt + (size_t)(n0 + row) * K + kcol;
        lBdst[t] = Bs + c * 8;
    }

    auto issue = [&](int k0, int st) {
#pragma unroll
        for (int t = 0; t < AT; ++t)
            if ((t + 1) * NT <= ACH || t * NT + tid < ACH)
                gl_lds16(gAsrc[t] + k0, lAdst[t] + st * ACH * 8);
#pragma unroll
        for (int t = 0; t < BT; ++t)
            if ((t + 1) * NT <= BCH || t * NT + tid < BCH)
                gl_lds16(gBsrc[t] + k0, lBdst[t] + st * BCH * 8);
    };

    floatx16 acc[MI][NI];
#pragma unroll
    for (int mi = 0; mi < MI; ++mi)
#pragma unroll
        for (int ni = 0; ni < NI; ++ni)
#pragma unroll
            for (int i = 0; i < 16; ++i) acc[mi][ni][i] = 0.f;

    auto compute = [&](int st) {
        const int ao = st * ACH * 8, bo = st * BCH * 8;
#pragma unroll
        for (int ks = 0; ks < 2; ++ks) {
            half8 af[MI], bf[NI];
#pragma unroll
            for (int mi = 0; mi < MI; ++mi)
                af[mi] = *(const half8*)(As + ao + ((size_t)(ks * TM * 2 + (wr * MI + mi) * 64 + lane)) * 8);
#pragma unroll
            for (int ni = 0; ni < NI; ++ni)
                bf[ni] = *(const half8*)(Bs + bo + ((size_t)(ks * TN * 2 + (wc * NI + ni) * 64 + lane)) * 8);
#pragma unroll
            for (int mi = 0; mi < MI; ++mi)
#pragma unroll
                for (int ni = 0; ni < NI; ++ni)
                    acc[mi][ni] = __builtin_amdgcn_mfma_f32_32x32x16_f16(af[mi], bf[ni], acc[mi][ni], 0, 0, 0);
        }
    };

    // --- depth-3 pipeline, one barrier per step, vmcnt never drains mid-loop ---
    const int ntiles = K / BK;
    issue(0, 0);
    if (ntiles > 1) issue(BK, 1);
    if (ntiles > 2) issue(2 * BK, 2);
    for (int kt = 0; kt < ntiles; ++kt) {
        const int rem = ntiles - 1 - kt;   // tiles after this one
        if (rem >= 2)      waitcnt_vm<2 * LPS>();  // own tile-kt loads landed
        else if (rem == 1) waitcnt_vm<LPS>();
        else               waitcnt_vm<0>();
        __builtin_amdgcn_s_barrier();       // everyone's tile-kt landed; buf (kt+3)&3 free
        asm volatile("" ::: "memory");
        __builtin_amdgcn_sched_barrier(0);
        if (kt + 3 < ntiles) issue((kt + 3) * BK, (kt + 3) & 3);
        __builtin_amdgcn_s_setprio(1);
        compute(kt & 3);
        __builtin_amdgcn_s_setprio(0);
        lgkm0();                            // own ds_reads of buf kt&3 done before overwrite
    }

    const int bf_ = *flagp;
    const int am = lane & 31;
    const int half = lane >> 5;

    if (g.fuse) {
        // fused tanh + ||c-a||, LDS-staged:
        //  a_s (reuses As): f32 a-tile [TM][32], conflict-free reads (lane=am -> bank)
        //  d_s (reuses Bs): [TM][8] per-block dist staging, then ONE coalesced copy-out
        const int ebase = n0 >> 5;          // global expert base of this n-tile
        float bvv[NI];
#pragma unroll
        for (int ni = 0; ni < NI; ++ni)
            bvv[ni] = ldraw(g.bias, (size_t)(n0 + (wc * NI + ni) * 32 + am), bf_);
        float* a_s = (float*)As;            // TM*128B <= NST*ACH*16B = TM*256B
        float* d_s = (float*)Bs;            // TM*32B  <= Bs size
        __syncthreads();
        for (int idx = tid; idx < TM * kA; idx += NT)
            a_s[idx] = ldraw(g.a_raw, (size_t)(m0 + (idx >> 5)) * kA + (idx & 31), bf_);
        __syncthreads();
#pragma unroll
        for (int mi = 0; mi < MI; ++mi)
#pragma unroll
            for (int rr = 0; rr < 16; ++rr) {
                const int row_loc = (wr * MI + mi) * 32 + (rr & 3) + 8 * (rr >> 2) + 4 * half;
                const float av = a_s[row_loc * kA + am];
#pragma unroll
                for (int ni = 0; ni < NI; ++ni) {
                    const float c = fast_tanh(acc[mi][ni][rr] + bvv[ni]);
                    const float d = c - av;
                    float d2 = d * d;
                    d2 += __shfl_xor(d2, 1);
                    d2 += __shfl_xor(d2, 2);
                    d2 += __shfl_xor(d2, 4);
                    d2 += __shfl_xor(d2, 8);
                    d2 += __shfl_xor(d2, 16);
                    if (am == 0) d_s[row_loc * 8 + wc * NI + ni] = d2;
                }
            }
        __syncthreads();
        for (int idx = tid; idx < TM * 8; idx += NT)
            g.dist[(size_t)(m0 + (idx >> 3)) * kN + ebase + (idx & 7)] = sqrtf(d_s[idx] + 0.01f);
        return;
    }

#pragma unroll
    for (int mi = 0; mi < MI; ++mi)
#pragma unroll
        for (int ni = 0; ni < NI; ++ni) {
            const int Rb = m0 + (wr * MI + mi) * 32;
            const int Cb = n0 + (wc * NI + ni) * 32 + am;
            const float bv = (Cb < g.split) ? ldraw(g.bias, Cb, bf_)
                                            : ldraw(g.bias2, Cb - g.split, bf_);
#pragma unroll
            for (int rr = 0; rr < 16; ++rr) {
                const int row = Rb + (rr & 3) + 8 * (rr >> 2) + 4 * half;
                float x = acc[mi][ni][rr] + bv;
                if (g.relu) x = fmaxf(x, 0.f);
                if (g.of16) ((_Float16*)g.C)[(size_t)row * N + Cb] = (_Float16)x;
                else ((float*)g.C)[(size_t)row * N + Cb] = x;
            }
        }
}

template <int TM, int TN, int WM, int WN>
__launch_bounds__(WM * WN * 64, 2)
__global__ void dgemm_one(GArgs g, const int* __restrict__ flagp) {
    dgemm_core<TM, TN, WM, WN>(g, blockIdx.x, flagp);
}

// --- slim final: softmax(-dist) . values, one wave per batch row
__launch_bounds__(256)
__global__ void final_softmax(const float* __restrict__ dist, const float* __restrict__ values,
                              const int* __restrict__ flag, void* __restrict__ out) {
    const int row = blockIdx.x * 4 + (threadIdx.x >> 6);
    const int lane = threadIdx.x & 63;
    const float4 d4 = *(const float4*)(dist + (size_t)row * kN + lane * 4);
    const float4 v4 = *(const float4*)(values + (size_t)row * kN + lane * 4);
    float m = fminf(fminf(d4.x, d4.y), fminf(d4.z, d4.w));
#pragma unroll
    for (int off = 32; off > 0; off >>= 1) m = fminf(m, __shfl_xor(m, off));
    const float w0 = expf(m - d4.x), w1 = expf(m - d4.y);
    const float w2 = expf(m - d4.z), w3 = expf(m - d4.w);
    float ws = (w0 + w1) + (w2 + w3);
    float wv = fmaf(w0, v4.x, fmaf(w1, v4.y, fmaf(w2, v4.z, w3 * v4.w)));
#pragma unroll
    for (int off = 32; off > 0; off >>= 1) {
        ws += __shfl_xor(ws, off);
        wv += __shfl_xor(wv, off);
    }
    if (lane == 0) {
        const float o = wv / ws;
        if (*flag) ((__hip_bfloat16*)out)[row] = __float2bfloat16(o);
        else       ((float*)out)[row] = o;
    }
}

extern "C" void kernel_launch(void* const* d_in, const int* in_sizes, int n_in,
                              void* d_out, int out_size, void* d_ws, size_t ws_size,
                              hipStream_t stream) {
    (void)in_sizes; (void)n_in; (void)out_size; (void)ws_size;
    char* ws = (char*)d_ws;
    int* flag = (int*)(ws + OFF_FLAG);
    _Float16* s16   = (_Float16*)(ws + OFF_S16);
    _Float16* wexpt = (_Float16*)(ws + OFF_WEXPT);
    _Float16* wv1t  = (_Float16*)(ws + OFF_WV1T);  // wl1t contiguous after -> [2048x128]
    _Float16* wl1t  = (_Float16*)(ws + OFF_WL1T);
    _Float16* wv2t  = (_Float16*)(ws + OFF_WV2T);
    _Float16* wv3t  = (_Float16*)(ws + OFF_WV3T);
    _Float16* wv4t  = (_Float16*)(ws + OFF_WV4T);
    _Float16* bufC  = (_Float16*)(ws + OFF_BUFC);  // [4096 x 2048]: h1 | hloc
    _Float16* b2v   = (_Float16*)(ws + OFF_B2V);
    _Float16* b3    = (_Float16*)(ws + OFF_B3);
    float* values   = (float*)(ws + OFF_VAL);
    float* distb    = (float*)(ws + OFF_DIST);

    detect_kernel<<<1, 256, 0, stream>>>((const unsigned int*)d_in[0], flag);

    TPack tp;
    tp.d[0] = {d_in[2],  wv1t,  kS, kH, (kH / 32) * (kS / 32)};          // 128
    tp.d[1] = {d_in[10], wl1t,  kS, kH, (kH / 32) * (kS / 32)};          // 128
    tp.d[2] = {d_in[4],  wv2t,  kH, kH, (kH / 32) * (kH / 32)};          // 1024
    tp.d[3] = {d_in[6],  wv3t,  kH, kH, (kH / 32) * (kH / 32)};          // 1024
    tp.d[4] = {d_in[8],  wv4t,  kH, kN, (kN / 32) * (kH / 32)};          // 256
    tp.d[5] = {d_in[12], wexpt, kH, kA, kN * (kA / 32) * (kH / 32)};     // 8192
    tp.d[6] = {d_in[0],  s16,   0,  kB * kS, (kB * kS) / 4096};          // 128 (convert)
    int total_tiles = 0;
    for (int i = 0; i < 7; ++i) total_tiles += tp.d[i].tiles;            // 10880
    transpose_all<<<total_tiles, dim3(8, 32), 0, stream>>>(tp, flag);

    const int BIG = 1 << 30;
    // fused gemm1+gemm5: bufC[4096x2048] = relu(s16 @ [wv1t;wl1t]^T + [bv1;bl1])
    {
        GArgs g{s16, wv1t, d_in[3], d_in[11], bufC, nullptr, nullptr, kH,
                2 * kH, kS, kS, kB / 64, (2 * kH) / 64, 1, 1, 0};
        dgemm_one<64, 64, 2, 2><<<(kB / 64) * ((2 * kH) / 64), 256, 0, stream>>>(g, flag);
    }
    // gemm2: b2v = relu(bufC[:, :1024] @ wv2t^T + bv2)
    {
        GArgs g{bufC, wv2t, d_in[5], d_in[5], b2v, nullptr, nullptr, BIG,
                kH, kH, 2 * kH, kB / 128, kH / 128, 1, 1, 0};
        dgemm_one<128, 128, 2, 2><<<(kB / 128) * (kH / 128), 256, 0, stream>>>(g, flag);
    }
    // gemm3: b3 = relu(b2v @ wv3t^T + bv3)
    {
        GArgs g{b2v, wv3t, d_in[7], d_in[7], b3, nullptr, nullptr, BIG,
                kH, kH, kH, kB / 128, kH / 128, 1, 1, 0};
        dgemm_one<128, 128, 2, 2><<<(kB / 128) * (kH / 128), 256, 0, stream>>>(g, flag);
    }
    // gemm4: values = b3 @ wv4t^T + bv4 (f32 out)
    {
        GArgs g{b3, wv4t, d_in[9], d_in[9], values, nullptr, nullptr, BIG,
                kN, kH, kH, kB / 64, kN / 64, 0, 0, 0};
        dgemm_one<64, 64, 2, 2><<<(kB / 64) * (kN / 64), 256, 0, stream>>>(g, flag);
    }
    // expert heads + fused distance: dist[B][N] = ||tanh(h@Wexp+bexp) - a||
    // 512 threads (WM=2,WN=4 -> MI=4,NI=2): 0.75KB LDS read per MFMA vs 1KB at 4x4.
    {
        GArgs g{bufC + kH, wexpt, d_in[13], d_in[13], nullptr, d_in[1], distb,
                BIG, kN * kA, kH, 2 * kH, kB / 256, (kN * kA) / 256, 0, 0, 1};
        dgemm_one<256, 256, 2, 4><<<(kB / 256) * ((kN * kA) / 256), 512, 0, stream>>>(g, flag);
    }
    // softmax over experts + value readout
    final_softmax<<<kB / 4, 256, 0, stream>>>(distb, values, flag, d_out);
}

// Round 3
// 343.790 us; speedup vs baseline: 1.2973x; 1.0986x over previous
//
#include <hip/hip_runtime.h>
#include <hip/hip_bf16.h>

// Net_40089224741482 round 18:
//  - r17 post-mortem: perf across r15/r16/r17 tracks blocks-per-CU (2/1/1), not
//    LDS-read-per-MFMA. Expert GEMM must stay in the 64KB-LDS / 2-blocks-per-CU
//    envelope; the second resident block is what hides barrier latency (m114).
//  - expert GEMM: back to 256x256 WM=WN=4 1024thr, NST=2 (64KB), but with
//    counted-vmcnt before the first barrier (no vmcnt(0) drain mid-loop) and
//    setprio(1) around the MFMA cluster. Fused dist epilogue kept (r17: WRITE
//    225->4MB proven).
//  - other GEMMs keep the NST=4 depth-3 single-barrier pipeline (r17: rest
//    199->169us).

typedef _Float16 half8 __attribute__((ext_vector_type(8)));
typedef _Float16 half4v __attribute__((ext_vector_type(4)));
typedef float floatx16 __attribute__((ext_vector_type(16)));

namespace {
constexpr int kB = 4096, kS = 128, kA = 32, kH = 1024, kN = 256;
constexpr size_t al(size_t x) { return (x + 255) & ~size_t(255); }
constexpr size_t OFF_FLAG  = 0;
constexpr size_t OFF_S16   = 256;
constexpr size_t OFF_WEXPT = OFF_S16   + al((size_t)kB * kS * 2);
constexpr size_t OFF_WV1T  = OFF_WEXPT + al((size_t)kN * kA * kH * 2);
constexpr size_t OFF_WL1T  = OFF_WV1T  + (size_t)kS * kH * 2;   // contiguous with WV1T
constexpr size_t OFF_WV2T  = OFF_WL1T  + al((size_t)kS * kH * 2);
constexpr size_t OFF_WV3T  = OFF_WV2T  + al((size_t)kH * kH * 2);
constexpr size_t OFF_WV4T  = OFF_WV3T  + al((size_t)kH * kH * 2);
constexpr size_t OFF_BUFC  = OFF_WV4T  + al((size_t)kH * kN * 2);
constexpr size_t OFF_B2V   = OFF_BUFC  + al((size_t)kB * 2 * kH * 2);
constexpr size_t OFF_B3    = OFF_B2V   + al((size_t)kB * kH * 2);
constexpr size_t OFF_VAL   = OFF_B3    + al((size_t)kB * kH * 2);
constexpr size_t OFF_DIST  = OFF_VAL   + al((size_t)kB * kN * 4);
} // namespace

__device__ __forceinline__ float ldraw(const void* p, size_t i, int bf) {
    if (bf) return __uint_as_float(((unsigned)((const unsigned short*)p)[i]) << 16);
    return ((const float*)p)[i];
}

__device__ __forceinline__ float4 ldraw4(const void* p, size_t i, int bf) {
    if (bf) {
        ushort4 u = *(const ushort4*)((const unsigned short*)p + i);
        return make_float4(__uint_as_float((unsigned)u.x << 16),
                           __uint_as_float((unsigned)u.y << 16),
                           __uint_as_float((unsigned)u.z << 16),
                           __uint_as_float((unsigned)u.w << 16));
    }
    return *(const float4*)((const float*)p + i);
}

__device__ __forceinline__ void gl_lds16(const _Float16* g, _Float16* l) {
    __builtin_amdgcn_global_load_lds(
        (const __attribute__((address_space(1))) unsigned int*)g,
        (__attribute__((address_space(3))) unsigned int*)l, 16, 0, 0);
}

template <int N>
__device__ __forceinline__ void waitcnt_vm() {
    if constexpr (N == 0)      asm volatile("s_waitcnt vmcnt(0)" ::: "memory");
    else if constexpr (N == 2) asm volatile("s_waitcnt vmcnt(2)" ::: "memory");
    else if constexpr (N == 4) asm volatile("s_waitcnt vmcnt(4)" ::: "memory");
    else if constexpr (N == 6) asm volatile("s_waitcnt vmcnt(6)" ::: "memory");
    else if constexpr (N == 8) asm volatile("s_waitcnt vmcnt(8)" ::: "memory");
    else if constexpr (N == 16) asm volatile("s_waitcnt vmcnt(16)" ::: "memory");
    else static_assert(N == 0, "unsupported vmcnt");
}
__device__ __forceinline__ void lgkm0() { asm volatile("s_waitcnt lgkmcnt(0)" ::: "memory"); }

__device__ __forceinline__ float fast_tanh(float x) {
    x = fminf(9.f, fmaxf(-9.f, x));
    float e = __expf(2.f * x);
    return (e - 1.f) * __builtin_amdgcn_rcpf(e + 1.f);
}

// --- dtype detection, parallel (fp32 low-16 = uniform mantissa; bf16-packed -> exp near 127)
__global__ void detect_kernel(const unsigned int* __restrict__ s_raw, int* __restrict__ flag) {
    __shared__ int cnt;
    if (threadIdx.x == 0) cnt = 0;
    __syncthreads();
    const unsigned e = (s_raw[threadIdx.x] >> 7) & 0xFFu;
    int c = (e >= 118u && e <= 135u) ? 1 : 0;
    for (int off = 32; off > 0; off >>= 1) c += __shfl_down(c, off);
    if ((threadIdx.x & 63) == 0) atomicAdd(&cnt, c);
    __syncthreads();
    if (threadIdx.x == 0) *flag = (cnt > 128) ? 1 : 0;
}

// --- ALL weight transposes + the s->f16 convert in ONE dispatch.
struct TDesc { const void* src; _Float16* dst; int K; int N; int tiles; };
struct TPack { TDesc d[7]; };

__global__ void transpose_all(TPack p, const int* __restrict__ flag) {
    __shared__ float tile[32][33];
    const int bf = *flag;
    int bid = blockIdx.x;
    int i = 0;
    while (bid >= p.d[i].tiles) { bid -= p.d[i].tiles; ++i; }
    const void* src = p.d[i].src;
    _Float16* dst = p.d[i].dst;
    const int tx = threadIdx.x, ty = threadIdx.y;  // tx 0..7, ty 0..31
    const int K = p.d[i].K, N = p.d[i].N;
    if (K == 0) {  // straight convert
        const int lin = ty * 8 + tx;
        const size_t base = (size_t)bid * 4096;
#pragma unroll
        for (int t = 0; t < 4; ++t) {
            const size_t idx = base + (size_t)t * 1024 + (size_t)lin * 4;
            float4 v = ldraw4(src, idx, bf);
            half4v o = {(_Float16)v.x, (_Float16)v.y, (_Float16)v.z, (_Float16)v.w};
            *(half4v*)(dst + idx) = o;
        }
        return;
    }
    const int tpz = (N >> 5) * (K >> 5);
    const int z = bid / tpz, r = bid - z * tpz;
    const int n0 = (r % (N >> 5)) * 32, k0 = (r / (N >> 5)) * 32;
    const size_t zo = (size_t)z * K * N;
    float4 v = ldraw4(src, zo + (size_t)(k0 + ty) * N + n0 + tx * 4, bf);
    tile[ty][tx * 4 + 0] = v.x;
    tile[ty][tx * 4 + 1] = v.y;
    tile[ty][tx * 4 + 2] = v.z;
    tile[ty][tx * 4 + 3] = v.w;
    __syncthreads();
    half4v o;
#pragma unroll
    for (int j = 0; j < 4; ++j) o[j] = (_Float16)tile[tx * 4 + j][ty];
    *(half4v*)(dst + zo + (size_t)(n0 + ty) * K + k0 + tx * 4) = o;
}

// --- GEMM argument pack
struct GArgs {
    const _Float16* A;
    const _Float16* Bt;
    const void* bias;
    const void* bias2;   // split-bias epilogue (fused gemm1+gemm5)
    void* C;
    const void* a_raw;   // fuse path: raw actions [B][kA]
    float* dist;         // fuse path: [B][kN] output
    int split;           // col < split -> bias[col], else bias2[col-split]
    int N, K, lda, Mt, Nt, relu, of16, fuse;
};

// --- core: MFMA GEMM, counted-vmcnt pipeline, fragment-order LDS,
// global_load_lds w16, XCD swizzle.
// NST=2: 2-barrier loop, 64KB-friendly (2 blocks/CU) -- for the big expert tile.
// NST=4: depth-3 single-barrier loop -- for small-LDS tiles.
template <int TM, int TN, int WM, int WN, int NST>
__device__ __forceinline__ void dgemm_core(const GArgs& g, int bid, const int* flagp) {
    constexpr int NT = WM * WN * 64;
    constexpr int BK = 32;
    constexpr int MI = TM / WM / 32, NI = TN / WN / 32;
    constexpr int ACH = TM * BK / 8;
    constexpr int BCH = TN * BK / 8;
    constexpr int AT = (ACH + NT - 1) / NT;
    constexpr int BT = (BCH + NT - 1) / NT;
    constexpr int LPS = AT + BT;           // gl_lds instrs per wave per stage
    __shared__ _Float16 As[NST * ACH * 8];
    __shared__ _Float16 Bs[NST * BCH * 8];

    const int tid = threadIdx.x;
    const int lane = tid & 63;
    const int w = tid >> 6, wr = w / WN, wc = w % WN;
    const int N = g.N, K = g.K, lda = g.lda;

    int mt, nt;
    if ((g.Mt & 7) == 0 && (g.Nt & 7) == 0) {
        const int xcd = bid & 7, loc = bid >> 3;
        const int Bn = g.Nt >> 3;
        const int sr = loc / (8 * Bn);
        const int rem = loc - sr * (8 * Bn);
        mt = sr * 8 + (rem & 7);
        nt = xcd * Bn + (rem >> 3);
    } else {
        mt = bid % g.Mt;
        nt = bid / g.Mt;
    }
    const int m0 = mt * TM, n0 = nt * TN;

    const _Float16* gAsrc[AT];
    _Float16* lAdst[AT];
#pragma unroll
    for (int t = 0; t < AT; ++t) {
        int c = t * NT + tid;
        if (c >= ACH) c = ACH - 1;
        const int ks = c / (TM * 2), rem = c % (TM * 2);
        const int row = (rem >> 6) * 32 + (rem & 31);
        const int kcol = ks * 16 + ((rem >> 5) & 1) * 8;
        gAsrc[t] = g.A + (size_t)(m0 + row) * lda + kcol;
        lAdst[t] = As + c * 8;
    }
    const _Float16* gBsrc[BT];
    _Float16* lBdst[BT];
#pragma unroll
    for (int t = 0; t < BT; ++t) {
        int c = t * NT + tid;
        if (c >= BCH) c = BCH - 1;
        const int ks = c / (TN * 2), rem = c % (TN * 2);
        const int row = (rem >> 6) * 32 + (rem & 31);
        const int kcol = ks * 16 + ((rem >> 5) & 1) * 8;
        gBsrc[t] = g.Bt + (size_t)(n0 + row) * K + kcol;
        lBdst[t] = Bs + c * 8;
    }

    auto issue = [&](int k0, int st) {
#pragma unroll
        for (int t = 0; t < AT; ++t)
            if ((t + 1) * NT <= ACH || t * NT + tid < ACH)
                gl_lds16(gAsrc[t] + k0, lAdst[t] + st * ACH * 8);
#pragma unroll
        for (int t = 0; t < BT; ++t)
            if ((t + 1) * NT <= BCH || t * NT + tid < BCH)
                gl_lds16(gBsrc[t] + k0, lBdst[t] + st * BCH * 8);
    };

    floatx16 acc[MI][NI];
#pragma unroll
    for (int mi = 0; mi < MI; ++mi)
#pragma unroll
        for (int ni = 0; ni < NI; ++ni)
#pragma unroll
            for (int i = 0; i < 16; ++i) acc[mi][ni][i] = 0.f;

    auto compute = [&](int st) {
        const int ao = st * ACH * 8, bo = st * BCH * 8;
#pragma unroll
        for (int ks = 0; ks < 2; ++ks) {
            half8 af[MI], bf[NI];
#pragma unroll
            for (int mi = 0; mi < MI; ++mi)
                af[mi] = *(const half8*)(As + ao + ((size_t)(ks * TM * 2 + (wr * MI + mi) * 64 + lane)) * 8);
#pragma unroll
            for (int ni = 0; ni < NI; ++ni)
                bf[ni] = *(const half8*)(Bs + bo + ((size_t)(ks * TN * 2 + (wc * NI + ni) * 64 + lane)) * 8);
#pragma unroll
            for (int mi = 0; mi < MI; ++mi)
#pragma unroll
                for (int ni = 0; ni < NI; ++ni)
                    acc[mi][ni] = __builtin_amdgcn_mfma_f32_32x32x16_f16(af[mi], bf[ni], acc[mi][ni], 0, 0, 0);
        }
    };

    const int ntiles = K / BK;
    if constexpr (NST == 2) {
        // 2-stage, 2-barrier loop with counted vmcnt (next tile stays in flight
        // across the first barrier -- no vmcnt(0) drain until the last tile).
        issue(0, 0);
        if (ntiles > 1) issue(BK, 1);
        for (int kt = 0; kt < ntiles; ++kt) {
            if (kt + 1 < ntiles) waitcnt_vm<LPS>();
            else                 waitcnt_vm<0>();
            __builtin_amdgcn_s_barrier();     // all waves' tile-kt loads landed
            asm volatile("" ::: "memory");
            __builtin_amdgcn_sched_barrier(0);
            __builtin_amdgcn_s_setprio(1);
            compute(kt & 1);
            __builtin_amdgcn_s_setprio(0);
            lgkm0();                           // own ds_reads of buf kt&1 done
            __builtin_amdgcn_s_barrier();     // all waves done reading buf kt&1
            if (kt + 2 < ntiles) issue((kt + 2) * BK, kt & 1);
        }
    } else {
        // 4-stage, depth-3 prefetch, ONE barrier per step.
        issue(0, 0);
        if (ntiles > 1) issue(BK, 1);
        if (ntiles > 2) issue(2 * BK, 2);
        for (int kt = 0; kt < ntiles; ++kt) {
            const int rem = ntiles - 1 - kt;   // tiles after this one
            if (rem >= 2)      waitcnt_vm<2 * LPS>();
            else if (rem == 1) waitcnt_vm<LPS>();
            else               waitcnt_vm<0>();
            __builtin_amdgcn_s_barrier();      // tile-kt landed; buf (kt+3)&3 free
            asm volatile("" ::: "memory");
            __builtin_amdgcn_sched_barrier(0);
            if (kt + 3 < ntiles) issue((kt + 3) * BK, (kt + 3) & 3);
            __builtin_amdgcn_s_setprio(1);
            compute(kt & 3);
            __builtin_amdgcn_s_setprio(0);
            lgkm0();                           // own ds_reads done before overwrite
        }
    }

    const int bf_ = *flagp;
    const int am = lane & 31;
    const int half = lane >> 5;

    if (g.fuse) {
        // fused tanh + ||c-a||, LDS-staged:
        //  a_s (reuses As): f32 a-tile [TM][32], conflict-free reads
        //  d_s (reuses Bs): [TM][8] dist staging, then ONE coalesced copy-out
        const int ebase = n0 >> 5;          // global expert base of this n-tile
        float bvv[NI];
#pragma unroll
        for (int ni = 0; ni < NI; ++ni)
            bvv[ni] = ldraw(g.bias, (size_t)(n0 + (wc * NI + ni) * 32 + am), bf_);
        float* a_s = (float*)As;            // TM*128B <= NST*ACH*16B (NST>=2)
        float* d_s = (float*)Bs;            // TM*32B
        __syncthreads();
        for (int idx = tid; idx < TM * kA; idx += NT)
            a_s[idx] = ldraw(g.a_raw, (size_t)(m0 + (idx >> 5)) * kA + (idx & 31), bf_);
        __syncthreads();
#pragma unroll
        for (int mi = 0; mi < MI; ++mi)
#pragma unroll
            for (int rr = 0; rr < 16; ++rr) {
                const int row_loc = (wr * MI + mi) * 32 + (rr & 3) + 8 * (rr >> 2) + 4 * half;
                const float av = a_s[row_loc * kA + am];
#pragma unroll
                for (int ni = 0; ni < NI; ++ni) {
                    const float c = fast_tanh(acc[mi][ni][rr] + bvv[ni]);
                    const float d = c - av;
                    float d2 = d * d;
                    d2 += __shfl_xor(d2, 1);
                    d2 += __shfl_xor(d2, 2);
                    d2 += __shfl_xor(d2, 4);
                    d2 += __shfl_xor(d2, 8);
                    d2 += __shfl_xor(d2, 16);
                    if (am == 0) d_s[row_loc * 8 + wc * NI + ni] = d2;
                }
            }
        __syncthreads();
        for (int idx = tid; idx < TM * 8; idx += NT)
            g.dist[(size_t)(m0 + (idx >> 3)) * kN + ebase + (idx & 7)] = sqrtf(d_s[idx] + 0.01f);
        return;
    }

#pragma unroll
    for (int mi = 0; mi < MI; ++mi)
#pragma unroll
        for (int ni = 0; ni < NI; ++ni) {
            const int Rb = m0 + (wr * MI + mi) * 32;
            const int Cb = n0 + (wc * NI + ni) * 32 + am;
            const float bv = (Cb < g.split) ? ldraw(g.bias, Cb, bf_)
                                            : ldraw(g.bias2, Cb - g.split, bf_);
#pragma unroll
            for (int rr = 0; rr < 16; ++rr) {
                const int row = Rb + (rr & 3) + 8 * (rr >> 2) + 4 * half;
                float x = acc[mi][ni][rr] + bv;
                if (g.relu) x = fmaxf(x, 0.f);
                if (g.of16) ((_Float16*)g.C)[(size_t)row * N + Cb] = (_Float16)x;
                else ((float*)g.C)[(size_t)row * N + Cb] = x;
            }
        }
}

template <int TM, int TN, int WM, int WN, int NST>
__launch_bounds__(WM * WN * 64, 2)
__global__ void dgemm_one(GArgs g, const int* __restrict__ flagp) {
    dgemm_core<TM, TN, WM, WN, NST>(g, blockIdx.x, flagp);
}

// --- slim final: softmax(-dist) . values, one wave per batch row
__launch_bounds__(256)
__global__ void final_softmax(const float* __restrict__ dist, const float* __restrict__ values,
                              const int* __restrict__ flag, void* __restrict__ out) {
    const int row = blockIdx.x * 4 + (threadIdx.x >> 6);
    const int lane = threadIdx.x & 63;
    const float4 d4 = *(const float4*)(dist + (size_t)row * kN + lane * 4);
    const float4 v4 = *(const float4*)(values + (size_t)row * kN + lane * 4);
    float m = fminf(fminf(d4.x, d4.y), fminf(d4.z, d4.w));
#pragma unroll
    for (int off = 32; off > 0; off >>= 1) m = fminf(m, __shfl_xor(m, off));
    const float w0 = expf(m - d4.x), w1 = expf(m - d4.y);
    const float w2 = expf(m - d4.z), w3 = expf(m - d4.w);
    float ws = (w0 + w1) + (w2 + w3);
    float wv = fmaf(w0, v4.x, fmaf(w1, v4.y, fmaf(w2, v4.z, w3 * v4.w)));
#pragma unroll
    for (int off = 32; off > 0; off >>= 1) {
        ws += __shfl_xor(ws, off);
        wv += __shfl_xor(wv, off);
    }
    if (lane == 0) {
        const float o = wv / ws;
        if (*flag) ((__hip_bfloat16*)out)[row] = __float2bfloat16(o);
        else       ((float*)out)[row] = o;
    }
}

extern "C" void kernel_launch(void* const* d_in, const int* in_sizes, int n_in,
                              void* d_out, int out_size, void* d_ws, size_t ws_size,
                              hipStream_t stream) {
    (void)in_sizes; (void)n_in; (void)out_size; (void)ws_size;
    char* ws = (char*)d_ws;
    int* flag = (int*)(ws + OFF_FLAG);
    _Float16* s16   = (_Float16*)(ws + OFF_S16);
    _Float16* wexpt = (_Float16*)(ws + OFF_WEXPT);
    _Float16* wv1t  = (_Float16*)(ws + OFF_WV1T);  // wl1t contiguous after -> [2048x128]
    _Float16* wl1t  = (_Float16*)(ws + OFF_WL1T);
    _Float16* wv2t  = (_Float16*)(ws + OFF_WV2T);
    _Float16* wv3t  = (_Float16*)(ws + OFF_WV3T);
    _Float16* wv4t  = (_Float16*)(ws + OFF_WV4T);
    _Float16* bufC  = (_Float16*)(ws + OFF_BUFC);  // [4096 x 2048]: h1 | hloc
    _Float16* b2v   = (_Float16*)(ws + OFF_B2V);
    _Float16* b3    = (_Float16*)(ws + OFF_B3);
    float* values   = (float*)(ws + OFF_VAL);
    float* distb    = (float*)(ws + OFF_DIST);

    detect_kernel<<<1, 256, 0, stream>>>((const unsigned int*)d_in[0], flag);

    TPack tp;
    tp.d[0] = {d_in[2],  wv1t,  kS, kH, (kH / 32) * (kS / 32)};          // 128
    tp.d[1] = {d_in[10], wl1t,  kS, kH, (kH / 32) * (kS / 32)};          // 128
    tp.d[2] = {d_in[4],  wv2t,  kH, kH, (kH / 32) * (kH / 32)};          // 1024
    tp.d[3] = {d_in[6],  wv3t,  kH, kH, (kH / 32) * (kH / 32)};          // 1024
    tp.d[4] = {d_in[8],  wv4t,  kH, kN, (kN / 32) * (kH / 32)};          // 256
    tp.d[5] = {d_in[12], wexpt, kH, kA, kN * (kA / 32) * (kH / 32)};     // 8192
    tp.d[6] = {d_in[0],  s16,   0,  kB * kS, (kB * kS) / 4096};          // 128 (convert)
    int total_tiles = 0;
    for (int i = 0; i < 7; ++i) total_tiles += tp.d[i].tiles;            // 10880
    transpose_all<<<total_tiles, dim3(8, 32), 0, stream>>>(tp, flag);

    const int BIG = 1 << 30;
    // fused gemm1+gemm5: bufC[4096x2048] = relu(s16 @ [wv1t;wl1t]^T + [bv1;bl1])
    {
        GArgs g{s16, wv1t, d_in[3], d_in[11], bufC, nullptr, nullptr, kH,
                2 * kH, kS, kS, kB / 64, (2 * kH) / 64, 1, 1, 0};
        dgemm_one<64, 64, 2, 2, 4><<<(kB / 64) * ((2 * kH) / 64), 256, 0, stream>>>(g, flag);
    }
    // gemm2: b2v = relu(bufC[:, :1024] @ wv2t^T + bv2)
    {
        GArgs g{bufC, wv2t, d_in[5], d_in[5], b2v, nullptr, nullptr, BIG,
                kH, kH, 2 * kH, kB / 128, kH / 128, 1, 1, 0};
        dgemm_one<128, 128, 2, 2, 4><<<(kB / 128) * (kH / 128), 256, 0, stream>>>(g, flag);
    }
    // gemm3: b3 = relu(b2v @ wv3t^T + bv3)
    {
        GArgs g{b2v, wv3t, d_in[7], d_in[7], b3, nullptr, nullptr, BIG,
                kH, kH, kH, kB / 128, kH / 128, 1, 1, 0};
        dgemm_one<128, 128, 2, 2, 4><<<(kB / 128) * (kH / 128), 256, 0, stream>>>(g, flag);
    }
    // gemm4: values = b3 @ wv4t^T + bv4 (f32 out)
    {
        GArgs g{b3, wv4t, d_in[9], d_in[9], values, nullptr, nullptr, BIG,
                kN, kH, kH, kB / 64, kN / 64, 0, 0, 0};
        dgemm_one<64, 64, 2, 2, 4><<<(kB / 64) * (kN / 64), 256, 0, stream>>>(g, flag);
    }
    // expert heads + fused distance: dist[B][N] = ||tanh(h@Wexp+bexp) - a||
    // 256x256, 4x4 waves, NST=2 -> 64KB LDS -> 2 blocks/CU (the r15 envelope),
    // counted-vmcnt + setprio on top.
    {
        GArgs g{bufC + kH, wexpt, d_in[13], d_in[13], nullptr, d_in[1], distb,
                BIG, kN * kA, kH, 2 * kH, kB / 256, (kN * kA) / 256, 0, 0, 1};
        dgemm_one<256, 256, 4, 4, 2><<<(kB / 256) * ((kN * kA) / 256), 1024, 0, stream>>>(g, flag);
    }
    // softmax over experts + value readout
    final_softmax<<<kB / 4, 256, 0, stream>>>(distb, values, flag, d_out);
}

// Round 4
// 339.857 us; speedup vs baseline: 1.3124x; 1.0116x over previous
//
#include <hip/hip_runtime.h>
#include <hip/hip_bf16.h>

// Net_40089224741482 round 19: consolidation of all proven-best parts.
//  - Cap analysis: per-wave-tile LDS-read cap = MI*NI/(4*(MI+NI)) = 25% at
//    MI=NI=2; r15 measured 25.5% -> r15's plain __syncthreads loop ACHIEVES its
//    structural cap. All pinned-schedule variants (r16/r17/r18) only lost.
//  - expert GEMM: exact r15 loop (2-phase dbuf, issue between barrier and
//    compute, NO setprio/sched_barrier) + r17's fused dist epilogue (WRITE
//    225->4MB proven) => removes the 64MB z-write from inside the loop.
//  - final stays slim final_softmax (r17: saved ~30us vs final_fused).
//  - small GEMMs keep the NST=4 depth-3 single-barrier pipeline.

typedef _Float16 half8 __attribute__((ext_vector_type(8)));
typedef _Float16 half4v __attribute__((ext_vector_type(4)));
typedef float floatx16 __attribute__((ext_vector_type(16)));

namespace {
constexpr int kB = 4096, kS = 128, kA = 32, kH = 1024, kN = 256;
constexpr size_t al(size_t x) { return (x + 255) & ~size_t(255); }
constexpr size_t OFF_FLAG  = 0;
constexpr size_t OFF_S16   = 256;
constexpr size_t OFF_WEXPT = OFF_S16   + al((size_t)kB * kS * 2);
constexpr size_t OFF_WV1T  = OFF_WEXPT + al((size_t)kN * kA * kH * 2);
constexpr size_t OFF_WL1T  = OFF_WV1T  + (size_t)kS * kH * 2;   // contiguous with WV1T
constexpr size_t OFF_WV2T  = OFF_WL1T  + al((size_t)kS * kH * 2);
constexpr size_t OFF_WV3T  = OFF_WV2T  + al((size_t)kH * kH * 2);
constexpr size_t OFF_WV4T  = OFF_WV3T  + al((size_t)kH * kH * 2);
constexpr size_t OFF_BUFC  = OFF_WV4T  + al((size_t)kH * kN * 2);
constexpr size_t OFF_B2V   = OFF_BUFC  + al((size_t)kB * 2 * kH * 2);
constexpr size_t OFF_B3    = OFF_B2V   + al((size_t)kB * kH * 2);
constexpr size_t OFF_VAL   = OFF_B3    + al((size_t)kB * kH * 2);
constexpr size_t OFF_DIST  = OFF_VAL   + al((size_t)kB * kN * 4);
} // namespace

__device__ __forceinline__ float ldraw(const void* p, size_t i, int bf) {
    if (bf) return __uint_as_float(((unsigned)((const unsigned short*)p)[i]) << 16);
    return ((const float*)p)[i];
}

__device__ __forceinline__ float4 ldraw4(const void* p, size_t i, int bf) {
    if (bf) {
        ushort4 u = *(const ushort4*)((const unsigned short*)p + i);
        return make_float4(__uint_as_float((unsigned)u.x << 16),
                           __uint_as_float((unsigned)u.y << 16),
                           __uint_as_float((unsigned)u.z << 16),
                           __uint_as_float((unsigned)u.w << 16));
    }
    return *(const float4*)((const float*)p + i);
}

__device__ __forceinline__ void gl_lds16(const _Float16* g, _Float16* l) {
    __builtin_amdgcn_global_load_lds(
        (const __attribute__((address_space(1))) unsigned int*)g,
        (__attribute__((address_space(3))) unsigned int*)l, 16, 0, 0);
}

template <int N>
__device__ __forceinline__ void waitcnt_vm() {
    if constexpr (N == 0)      asm volatile("s_waitcnt vmcnt(0)" ::: "memory");
    else if constexpr (N == 2) asm volatile("s_waitcnt vmcnt(2)" ::: "memory");
    else if constexpr (N == 4) asm volatile("s_waitcnt vmcnt(4)" ::: "memory");
    else if constexpr (N == 6) asm volatile("s_waitcnt vmcnt(6)" ::: "memory");
    else if constexpr (N == 8) asm volatile("s_waitcnt vmcnt(8)" ::: "memory");
    else if constexpr (N == 16) asm volatile("s_waitcnt vmcnt(16)" ::: "memory");
    else static_assert(N == 0, "unsupported vmcnt");
}

__device__ __forceinline__ float fast_tanh(float x) {
    x = fminf(9.f, fmaxf(-9.f, x));
    float e = __expf(2.f * x);
    return (e - 1.f) * __builtin_amdgcn_rcpf(e + 1.f);
}

// --- dtype detection, parallel (fp32 low-16 = uniform mantissa; bf16-packed -> exp near 127)
__global__ void detect_kernel(const unsigned int* __restrict__ s_raw, int* __restrict__ flag) {
    __shared__ int cnt;
    if (threadIdx.x == 0) cnt = 0;
    __syncthreads();
    const unsigned e = (s_raw[threadIdx.x] >> 7) & 0xFFu;
    int c = (e >= 118u && e <= 135u) ? 1 : 0;
    for (int off = 32; off > 0; off >>= 1) c += __shfl_down(c, off);
    if ((threadIdx.x & 63) == 0) atomicAdd(&cnt, c);
    __syncthreads();
    if (threadIdx.x == 0) *flag = (cnt > 128) ? 1 : 0;
}

// --- ALL weight transposes + the s->f16 convert in ONE dispatch.
struct TDesc { const void* src; _Float16* dst; int K; int N; int tiles; };
struct TPack { TDesc d[7]; };

__global__ void transpose_all(TPack p, const int* __restrict__ flag) {
    __shared__ float tile[32][33];
    const int bf = *flag;
    int bid = blockIdx.x;
    int i = 0;
    while (bid >= p.d[i].tiles) { bid -= p.d[i].tiles; ++i; }
    const void* src = p.d[i].src;
    _Float16* dst = p.d[i].dst;
    const int tx = threadIdx.x, ty = threadIdx.y;  // tx 0..7, ty 0..31
    const int K = p.d[i].K, N = p.d[i].N;
    if (K == 0) {  // straight convert
        const int lin = ty * 8 + tx;
        const size_t base = (size_t)bid * 4096;
#pragma unroll
        for (int t = 0; t < 4; ++t) {
            const size_t idx = base + (size_t)t * 1024 + (size_t)lin * 4;
            float4 v = ldraw4(src, idx, bf);
            half4v o = {(_Float16)v.x, (_Float16)v.y, (_Float16)v.z, (_Float16)v.w};
            *(half4v*)(dst + idx) = o;
        }
        return;
    }
    const int tpz = (N >> 5) * (K >> 5);
    const int z = bid / tpz, r = bid - z * tpz;
    const int n0 = (r % (N >> 5)) * 32, k0 = (r / (N >> 5)) * 32;
    const size_t zo = (size_t)z * K * N;
    float4 v = ldraw4(src, zo + (size_t)(k0 + ty) * N + n0 + tx * 4, bf);
    tile[ty][tx * 4 + 0] = v.x;
    tile[ty][tx * 4 + 1] = v.y;
    tile[ty][tx * 4 + 2] = v.z;
    tile[ty][tx * 4 + 3] = v.w;
    __syncthreads();
    half4v o;
#pragma unroll
    for (int j = 0; j < 4; ++j) o[j] = (_Float16)tile[tx * 4 + j][ty];
    *(half4v*)(dst + zo + (size_t)(n0 + ty) * K + k0 + tx * 4) = o;
}

// --- GEMM argument pack
struct GArgs {
    const _Float16* A;
    const _Float16* Bt;
    const void* bias;
    const void* bias2;   // split-bias epilogue (fused gemm1+gemm5)
    void* C;
    const void* a_raw;   // fuse path: raw actions [B][kA]
    float* dist;         // fuse path: [B][kN] output
    int split;           // col < split -> bias[col], else bias2[col-split]
    int N, K, lda, Mt, Nt, relu, of16, fuse;
};

// --- core: MFMA GEMM, fragment-order LDS, global_load_lds w16, XCD swizzle.
// NST=2: r15's plain 2-phase __syncthreads loop (measured AT its 25% LDS cap;
//        every pinned-schedule variant regressed) -- for the big expert tile.
// NST=4: depth-3 counted-vmcnt single-barrier loop -- for small-LDS tiles.
template <int TM, int TN, int WM, int WN, int NST>
__device__ __forceinline__ void dgemm_core(const GArgs& g, int bid, const int* flagp) {
    constexpr int NT = WM * WN * 64;
    constexpr int BK = 32;
    constexpr int MI = TM / WM / 32, NI = TN / WN / 32;
    constexpr int ACH = TM * BK / 8;
    constexpr int BCH = TN * BK / 8;
    constexpr int AT = (ACH + NT - 1) / NT;
    constexpr int BT = (BCH + NT - 1) / NT;
    constexpr int LPS = AT + BT;           // gl_lds instrs per wave per stage
    __shared__ _Float16 As[NST * ACH * 8];
    __shared__ _Float16 Bs[NST * BCH * 8];

    const int tid = threadIdx.x;
    const int lane = tid & 63;
    const int w = tid >> 6, wr = w / WN, wc = w % WN;
    const int N = g.N, K = g.K, lda = g.lda;

    int mt, nt;
    if ((g.Mt & 7) == 0 && (g.Nt & 7) == 0) {
        const int xcd = bid & 7, loc = bid >> 3;
        const int Bn = g.Nt >> 3;
        const int sr = loc / (8 * Bn);
        const int rem = loc - sr * (8 * Bn);
        mt = sr * 8 + (rem & 7);
        nt = xcd * Bn + (rem >> 3);
    } else {
        mt = bid % g.Mt;
        nt = bid / g.Mt;
    }
    const int m0 = mt * TM, n0 = nt * TN;

    const _Float16* gAsrc[AT];
    _Float16* lAdst[AT];
#pragma unroll
    for (int t = 0; t < AT; ++t) {
        int c = t * NT + tid;
        if (c >= ACH) c = ACH - 1;
        const int ks = c / (TM * 2), rem = c % (TM * 2);
        const int row = (rem >> 6) * 32 + (rem & 31);
        const int kcol = ks * 16 + ((rem >> 5) & 1) * 8;
        gAsrc[t] = g.A + (size_t)(m0 + row) * lda + kcol;
        lAdst[t] = As + c * 8;
    }
    const _Float16* gBsrc[BT];
    _Float16* lBdst[BT];
#pragma unroll
    for (int t = 0; t < BT; ++t) {
        int c = t * NT + tid;
        if (c >= BCH) c = BCH - 1;
        const int ks = c / (TN * 2), rem = c % (TN * 2);
        const int row = (rem >> 6) * 32 + (rem & 31);
        const int kcol = ks * 16 + ((rem >> 5) & 1) * 8;
        gBsrc[t] = g.Bt + (size_t)(n0 + row) * K + kcol;
        lBdst[t] = Bs + c * 8;
    }

    auto issue = [&](int k0, int st) {
#pragma unroll
        for (int t = 0; t < AT; ++t)
            if ((t + 1) * NT <= ACH || t * NT + tid < ACH)
                gl_lds16(gAsrc[t] + k0, lAdst[t] + st * ACH * 8);
#pragma unroll
        for (int t = 0; t < BT; ++t)
            if ((t + 1) * NT <= BCH || t * NT + tid < BCH)
                gl_lds16(gBsrc[t] + k0, lBdst[t] + st * BCH * 8);
    };

    floatx16 acc[MI][NI];
#pragma unroll
    for (int mi = 0; mi < MI; ++mi)
#pragma unroll
        for (int ni = 0; ni < NI; ++ni)
#pragma unroll
            for (int i = 0; i < 16; ++i) acc[mi][ni][i] = 0.f;

    auto compute = [&](int st) {
        const int ao = st * ACH * 8, bo = st * BCH * 8;
#pragma unroll
        for (int ks = 0; ks < 2; ++ks) {
            half8 af[MI], bf[NI];
#pragma unroll
            for (int mi = 0; mi < MI; ++mi)
                af[mi] = *(const half8*)(As + ao + ((size_t)(ks * TM * 2 + (wr * MI + mi) * 64 + lane)) * 8);
#pragma unroll
            for (int ni = 0; ni < NI; ++ni)
                bf[ni] = *(const half8*)(Bs + bo + ((size_t)(ks * TN * 2 + (wc * NI + ni) * 64 + lane)) * 8);
#pragma unroll
            for (int mi = 0; mi < MI; ++mi)
#pragma unroll
                for (int ni = 0; ni < NI; ++ni)
                    acc[mi][ni] = __builtin_amdgcn_mfma_f32_32x32x16_f16(af[mi], bf[ni], acc[mi][ni], 0, 0, 0);
        }
    };

    const int ntiles = K / BK;
    if constexpr (NST == 2) {
        // exact r15 structure: plain __syncthreads double-buffer, issue placed
        // between the barrier and compute. Measured at its structural cap.
        issue(0, 0);
        for (int k0 = 0; k0 < K; k0 += 2 * BK) {
            __syncthreads();
            if (k0 + BK < K) issue(k0 + BK, 1);
            compute(0);
            __syncthreads();
            if (k0 + 2 * BK < K) issue(k0 + 2 * BK, 0);
            compute(1);
        }
    } else {
        // 4-stage, depth-3 prefetch, ONE barrier per step, counted vmcnt.
        issue(0, 0);
        if (ntiles > 1) issue(BK, 1);
        if (ntiles > 2) issue(2 * BK, 2);
        for (int kt = 0; kt < ntiles; ++kt) {
            const int rem = ntiles - 1 - kt;   // tiles after this one
            if (rem >= 2)      waitcnt_vm<2 * LPS>();
            else if (rem == 1) waitcnt_vm<LPS>();
            else               waitcnt_vm<0>();
            __builtin_amdgcn_s_barrier();      // tile-kt landed; buf (kt+3)&3 free
            asm volatile("" ::: "memory");
            __builtin_amdgcn_sched_barrier(0);
            if (kt + 3 < ntiles) issue((kt + 3) * BK, (kt + 3) & 3);
            __builtin_amdgcn_s_setprio(1);
            compute(kt & 3);
            __builtin_amdgcn_s_setprio(0);
            asm volatile("s_waitcnt lgkmcnt(0)" ::: "memory"); // own ds_reads done
        }
    }

    const int bf_ = *flagp;
    const int am = lane & 31;
    const int half = lane >> 5;

    if (g.fuse) {
        // fused tanh + ||c-a||, LDS-staged:
        //  a_s (reuses As): f32 a-tile [TM][32], conflict-free reads
        //  d_s (reuses Bs): [TM][8] dist staging, then ONE coalesced copy-out
        const int ebase = n0 >> 5;          // global expert base of this n-tile
        float bvv[NI];
#pragma unroll
        for (int ni = 0; ni < NI; ++ni)
            bvv[ni] = ldraw(g.bias, (size_t)(n0 + (wc * NI + ni) * 32 + am), bf_);
        float* a_s = (float*)As;            // TM*128B <= NST*ACH*16B (NST>=2)
        float* d_s = (float*)Bs;            // TM*32B
        __syncthreads();
        for (int idx = tid; idx < TM * kA; idx += NT)
            a_s[idx] = ldraw(g.a_raw, (size_t)(m0 + (idx >> 5)) * kA + (idx & 31), bf_);
        __syncthreads();
#pragma unroll
        for (int mi = 0; mi < MI; ++mi)
#pragma unroll
            for (int rr = 0; rr < 16; ++rr) {
                const int row_loc = (wr * MI + mi) * 32 + (rr & 3) + 8 * (rr >> 2) + 4 * half;
                const float av = a_s[row_loc * kA + am];
#pragma unroll
                for (int ni = 0; ni < NI; ++ni) {
                    const float c = fast_tanh(acc[mi][ni][rr] + bvv[ni]);
                    const float d = c - av;
                    float d2 = d * d;
                    d2 += __shfl_xor(d2, 1);
                    d2 += __shfl_xor(d2, 2);
                    d2 += __shfl_xor(d2, 4);
                    d2 += __shfl_xor(d2, 8);
                    d2 += __shfl_xor(d2, 16);
                    if (am == 0) d_s[row_loc * 8 + wc * NI + ni] = d2;
                }
            }
        __syncthreads();
        for (int idx = tid; idx < TM * 8; idx += NT)
            g.dist[(size_t)(m0 + (idx >> 3)) * kN + ebase + (idx & 7)] = sqrtf(d_s[idx] + 0.01f);
        return;
    }

#pragma unroll
    for (int mi = 0; mi < MI; ++mi)
#pragma unroll
        for (int ni = 0; ni < NI; ++ni) {
            const int Rb = m0 + (wr * MI + mi) * 32;
            const int Cb = n0 + (wc * NI + ni) * 32 + am;
            const float bv = (Cb < g.split) ? ldraw(g.bias, Cb, bf_)
                                            : ldraw(g.bias2, Cb - g.split, bf_);
#pragma unroll
            for (int rr = 0; rr < 16; ++rr) {
                const int row = Rb + (rr & 3) + 8 * (rr >> 2) + 4 * half;
                float x = acc[mi][ni][rr] + bv;
                if (g.relu) x = fmaxf(x, 0.f);
                if (g.of16) ((_Float16*)g.C)[(size_t)row * N + Cb] = (_Float16)x;
                else ((float*)g.C)[(size_t)row * N + Cb] = x;
            }
        }
}

template <int TM, int TN, int WM, int WN, int NST>
__launch_bounds__(WM * WN * 64, 2)
__global__ void dgemm_one(GArgs g, const int* __restrict__ flagp) {
    dgemm_core<TM, TN, WM, WN, NST>(g, blockIdx.x, flagp);
}

// --- slim final: softmax(-dist) . values, one wave per batch row
__launch_bounds__(256)
__global__ void final_softmax(const float* __restrict__ dist, const float* __restrict__ values,
                              const int* __restrict__ flag, void* __restrict__ out) {
    const int row = blockIdx.x * 4 + (threadIdx.x >> 6);
    const int lane = threadIdx.x & 63;
    const float4 d4 = *(const float4*)(dist + (size_t)row * kN + lane * 4);
    const float4 v4 = *(const float4*)(values + (size_t)row * kN + lane * 4);
    float m = fminf(fminf(d4.x, d4.y), fminf(d4.z, d4.w));
#pragma unroll
    for (int off = 32; off > 0; off >>= 1) m = fminf(m, __shfl_xor(m, off));
    const float w0 = expf(m - d4.x), w1 = expf(m - d4.y);
    const float w2 = expf(m - d4.z), w3 = expf(m - d4.w);
    float ws = (w0 + w1) + (w2 + w3);
    float wv = fmaf(w0, v4.x, fmaf(w1, v4.y, fmaf(w2, v4.z, w3 * v4.w)));
#pragma unroll
    for (int off = 32; off > 0; off >>= 1) {
        ws += __shfl_xor(ws, off);
        wv += __shfl_xor(wv, off);
    }
    if (lane == 0) {
        const float o = wv / ws;
        if (*flag) ((__hip_bfloat16*)out)[row] = __float2bfloat16(o);
        else       ((float*)out)[row] = o;
    }
}

extern "C" void kernel_launch(void* const* d_in, const int* in_sizes, int n_in,
                              void* d_out, int out_size, void* d_ws, size_t ws_size,
                              hipStream_t stream) {
    (void)in_sizes; (void)n_in; (void)out_size; (void)ws_size;
    char* ws = (char*)d_ws;
    int* flag = (int*)(ws + OFF_FLAG);
    _Float16* s16   = (_Float16*)(ws + OFF_S16);
    _Float16* wexpt = (_Float16*)(ws + OFF_WEXPT);
    _Float16* wv1t  = (_Float16*)(ws + OFF_WV1T);  // wl1t contiguous after -> [2048x128]
    _Float16* wl1t  = (_Float16*)(ws + OFF_WL1T);
    _Float16* wv2t  = (_Float16*)(ws + OFF_WV2T);
    _Float16* wv3t  = (_Float16*)(ws + OFF_WV3T);
    _Float16* wv4t  = (_Float16*)(ws + OFF_WV4T);
    _Float16* bufC  = (_Float16*)(ws + OFF_BUFC);  // [4096 x 2048]: h1 | hloc
    _Float16* b2v   = (_Float16*)(ws + OFF_B2V);
    _Float16* b3    = (_Float16*)(ws + OFF_B3);
    float* values   = (float*)(ws + OFF_VAL);
    float* distb    = (float*)(ws + OFF_DIST);

    detect_kernel<<<1, 256, 0, stream>>>((const unsigned int*)d_in[0], flag);

    TPack tp;
    tp.d[0] = {d_in[2],  wv1t,  kS, kH, (kH / 32) * (kS / 32)};          // 128
    tp.d[1] = {d_in[10], wl1t,  kS, kH, (kH / 32) * (kS / 32)};          // 128
    tp.d[2] = {d_in[4],  wv2t,  kH, kH, (kH / 32) * (kH / 32)};          // 1024
    tp.d[3] = {d_in[6],  wv3t,  kH, kH, (kH / 32) * (kH / 32)};          // 1024
    tp.d[4] = {d_in[8],  wv4t,  kH, kN, (kN / 32) * (kH / 32)};          // 256
    tp.d[5] = {d_in[12], wexpt, kH, kA, kN * (kA / 32) * (kH / 32)};     // 8192
    tp.d[6] = {d_in[0],  s16,   0,  kB * kS, (kB * kS) / 4096};          // 128 (convert)
    int total_tiles = 0;
    for (int i = 0; i < 7; ++i) total_tiles += tp.d[i].tiles;            // 10880
    transpose_all<<<total_tiles, dim3(8, 32), 0, stream>>>(tp, flag);

    const int BIG = 1 << 30;
    // fused gemm1+gemm5: bufC[4096x2048] = relu(s16 @ [wv1t;wl1t]^T + [bv1;bl1])
    {
        GArgs g{s16, wv1t, d_in[3], d_in[11], bufC, nullptr, nullptr, kH,
                2 * kH, kS, kS, kB / 64, (2 * kH) / 64, 1, 1, 0};
        dgemm_one<64, 64, 2, 2, 4><<<(kB / 64) * ((2 * kH) / 64), 256, 0, stream>>>(g, flag);
    }
    // gemm2: b2v = relu(bufC[:, :1024] @ wv2t^T + bv2)
    {
        GArgs g{bufC, wv2t, d_in[5], d_in[5], b2v, nullptr, nullptr, BIG,
                kH, kH, 2 * kH, kB / 128, kH / 128, 1, 1, 0};
        dgemm_one<128, 128, 2, 2, 4><<<(kB / 128) * (kH / 128), 256, 0, stream>>>(g, flag);
    }
    // gemm3: b3 = relu(b2v @ wv3t^T + bv3)
    {
        GArgs g{b2v, wv3t, d_in[7], d_in[7], b3, nullptr, nullptr, BIG,
                kH, kH, kH, kB / 128, kH / 128, 1, 1, 0};
        dgemm_one<128, 128, 2, 2, 4><<<(kB / 128) * (kH / 128), 256, 0, stream>>>(g, flag);
    }
    // gemm4: values = b3 @ wv4t^T + bv4 (f32 out)
    {
        GArgs g{b3, wv4t, d_in[9], d_in[9], values, nullptr, nullptr, BIG,
                kN, kH, kH, kB / 64, kN / 64, 0, 0, 0};
        dgemm_one<64, 64, 2, 2, 4><<<(kB / 64) * (kN / 64), 256, 0, stream>>>(g, flag);
    }
    // expert heads + fused distance: dist[B][N] = ||tanh(h@Wexp+bexp) - a||
    // 256x256, 4x4 waves, NST=2 (64KB), exact r15 loop (at structural cap).
    {
        GArgs g{bufC + kH, wexpt, d_in[13], d_in[13], nullptr, d_in[1], distb,
                BIG, kN * kA, kH, 2 * kH, kB / 256, (kN * kA) / 256, 0, 0, 1};
        dgemm_one<256, 256, 4, 4, 2><<<(kB / 256) * ((kN * kA) / 256), 1024, 0, stream>>>(g, flag);
    }
    // softmax over experts + value readout
    final_softmax<<<kB / 4, 256, 0, stream>>>(distb, values, flag, d_out);
}